// Round 21
// baseline (4430.360 us; speedup 1.0000x reference)
//
#include <hip/hip_runtime.h>

// Residual VQ — bf16-MFMA screen + np-exact rescore. Round 21: DEEP ASYNC
// b-pipeline. r15-r20 synthesis: wall = serial 1-deep load->MFMA chain (32
// exposed latency events/wave/level); regs can't deepen it. Fix: b fragments
// stream via global_load_lds into a wave-private 6-slot LDS ring with counted
// vmcnt (T3/T4): 10 loads in flight, zero VGPR cost, no barriers (single-wave
// producer=consumer). a-fragments in 32 regs (r19-validated). Decision
// arithmetic byte-identical to r14-r20 PASS; async races would only corrupt
// the screen -> alarm -> exact full scan (correct, slow).

#define NTOK 131072
#define DEPTH 8
#define KCB 1024
#define DIM 256
#define TM 16
#define RP 260
#define WWIN 0.12f
#define ALARM 0.05f
#define LCAP 64

typedef __attribute__((ext_vector_type(8))) short short8v;
typedef __attribute__((ext_vector_type(4))) float f32x4;

#define WVM(n) asm volatile("s_waitcnt vmcnt(" #n ")" ::: "memory")
#define WLK(n) asm volatile("s_waitcnt lgkmcnt(" #n ")" ::: "memory")
#define SBAR() __builtin_amdgcn_sched_barrier(0)

__device__ __forceinline__ void gload16(const unsigned short* g,
                                        unsigned short* l) {
  __builtin_amdgcn_global_load_lds(
      (__attribute__((address_space(1))) const void*)g,
      (__attribute__((address_space(3))) void*)l, 16, 0, 0);
}

__device__ __forceinline__ unsigned short f32_to_bf16_rne(float f) {
  unsigned int u = __float_as_uint(f);
  return (unsigned short)((u + 0x7FFFu + ((u >> 16) & 1u)) >> 16);
}

__device__ __forceinline__ unsigned int fkey(float f) {
  unsigned int b = __float_as_uint(f);
  return (b & 0x80000000u) ? ~b : (b | 0x80000000u);
}
__device__ __forceinline__ float finv(unsigned int k) {
  return (k & 0x80000000u) ? __uint_as_float(k ^ 0x80000000u)
                           : __uint_as_float(~k);
}

__device__ __forceinline__ float np_sumsq_128(const float* p) {
  float s[16];
#pragma unroll
  for (int l = 0; l < 16; ++l) {
    float r0 = __fadd_rn(__fmul_rn(p[l], p[l]),
                         __fmul_rn(p[l + 64], p[l + 64]));
    float r1 = __fadd_rn(__fmul_rn(p[l + 16], p[l + 16]),
                         __fmul_rn(p[l + 80], p[l + 80]));
    float r2 = __fadd_rn(__fmul_rn(p[l + 32], p[l + 32]),
                         __fmul_rn(p[l + 96], p[l + 96]));
    float r3 = __fadd_rn(__fmul_rn(p[l + 48], p[l + 48]),
                         __fmul_rn(p[l + 112], p[l + 112]));
    s[l] = __fadd_rn(__fadd_rn(r0, r1), __fadd_rn(r2, r3));
  }
  float t[8];
#pragma unroll
  for (int l = 0; l < 8; ++l) t[l] = __fadd_rn(s[l], s[l + 8]);
  float u[4];
#pragma unroll
  for (int l = 0; l < 4; ++l) u[l] = __fadd_rn(t[l], t[l + 4]);
  return __fadd_rn(__fadd_rn(u[0], u[2]), __fadd_rn(u[1], u[3]));
}

__device__ __forceinline__ float np_sumsq_256(const float* p) {
  return __fadd_rn(np_sumsq_128(p), np_sumsq_128(p + 128));
}

// 16-lane-parallel replica of np_sumsq_256's exact add tree (r18-validated).
__device__ __forceinline__ float np_sumsq_256_par(const float* p, int kc) {
  float half[2];
#pragma unroll
  for (int h = 0; h < 2; ++h) {
    const float* q = p + h * 128;
    float r0 = __fadd_rn(__fmul_rn(q[kc], q[kc]),
                         __fmul_rn(q[kc + 64], q[kc + 64]));
    float r1 = __fadd_rn(__fmul_rn(q[kc + 16], q[kc + 16]),
                         __fmul_rn(q[kc + 80], q[kc + 80]));
    float r2 = __fadd_rn(__fmul_rn(q[kc + 32], q[kc + 32]),
                         __fmul_rn(q[kc + 96], q[kc + 96]));
    float r3 = __fadd_rn(__fmul_rn(q[kc + 48], q[kc + 48]),
                         __fmul_rn(q[kc + 112], q[kc + 112]));
    float s = __fadd_rn(__fadd_rn(r0, r1), __fadd_rn(r2, r3));
    float t = __fadd_rn(s, __shfl_down(s, 8, 16));
    float u = __fadd_rn(t, __shfl_down(t, 4, 16));
    float v = __fadd_rn(u, __shfl_down(u, 2, 16));
    half[h] = __fadd_rn(v, __shfl_down(v, 1, 16));
  }
  return __fadd_rn(half[0], half[1]);
}

__device__ __forceinline__ float np_dist(const float* rrow, const float* crow,
                                         float A, float C) {
  float dot = 0.f;
#pragma unroll 8
  for (int q = 0; q < 64; ++q) {
    float4 rv = *(const float4*)(rrow + q * 4);
    float4 cv = *(const float4*)(crow + q * 4);
    dot = fmaf(rv.x, cv.x, dot);
    dot = fmaf(rv.y, cv.y, dot);
    dot = fmaf(rv.z, cv.z, dot);
    dot = fmaf(rv.w, cv.w, dot);
  }
  return __fadd_rn(__fsub_rn(A, __fmul_rn(2.0f, dot)), C);
}

__global__ __launch_bounds__(256) void c2_kernel(const float* __restrict__ cbs,
                                                 float* __restrict__ C32g) {
  int gid = blockIdx.x * 256 + threadIdx.x;
  C32g[gid] = np_sumsq_256(cbs + (size_t)gid * DIM);
}

// cbf[(((lvl*64+g)*8+s)*64+lane)*8 + j] = bf16(cbs[lvl][g*16+(lane&15)]
//                                              [s*32+(lane>>4)*8+j])
__global__ __launch_bounds__(256) void pack_kernel(
    const float* __restrict__ cbs, unsigned short* __restrict__ cbf) {
  int gid = blockIdx.x * 256 + threadIdx.x;  // 262144
  int lane = gid & 63;
  int s = (gid >> 6) & 7;
  int g = (gid >> 9) & 63;
  int lvl = gid >> 15;
  int kcol = g * 16 + (lane & 15);
  int kd0 = s * 32 + (lane >> 4) * 8;
  const float* src = cbs + ((size_t)lvl * KCB + kcol) * DIM + kd0;
  unsigned short t[8];
#pragma unroll
  for (int j = 0; j < 8; ++j) t[j] = f32_to_bf16_rne(src[j]);
  ushort4 lo = {t[0], t[1], t[2], t[3]};
  ushort4 hi = {t[4], t[5], t[6], t[7]};
  *(ushort4*)(cbf + (size_t)gid * 8) = lo;
  *(ushort4*)(cbf + (size_t)gid * 8 + 4) = hi;
}

__global__ __launch_bounds__(256, 4) void rvq_kernel(
    const float* __restrict__ latent, const float* __restrict__ cbs,
    const float* __restrict__ C32g, const unsigned short* __restrict__ cbf,
    float* __restrict__ out) {
  __shared__ float r_m[TM][RP];                            // 16.6 KB
  __shared__ __align__(16) unsigned short ringS[4][6144];  // 48 KB ring
  __shared__ float A_s[TM];
  __shared__ unsigned int gkey[TM];
  __shared__ int cnt[TM];
  __shared__ int list[TM][LCAP];
  __shared__ int idx_s[TM];

  const int tid = threadIdx.x;
  const int w = tid >> 6;
  const int lane = tid & 63;
  const int lc = lane & 15;
  const int lg = lane >> 4;
  const int n0 = blockIdx.x * TM;

  // ---- stage latent -> r_m (exact); init gkey/cnt ----
  {
    int tok = tid >> 4;
    int db = (tid & 15) * 16;
    const float* src = latent + (size_t)(n0 + tok) * DIM + db;
#pragma unroll
    for (int j = 0; j < 4; ++j)
      *(float4*)&r_m[tok][db + j * 4] = *(const float4*)(src + j * 4);
    if (tid < TM) {
      gkey[tid] = 0xFFFFFFFFu;
      cnt[tid] = 0;
    }
  }
  __syncthreads();

  for (int lvl = 0; lvl < DEPTH; ++lvl) {
    const float* cb = cbs + (size_t)lvl * KCB * DIM;

    // exact A per token (np tree)
    {
      float A = np_sumsq_256_par(&r_m[tid >> 4][0], tid & 15);
      if ((tid & 15) == 0) A_s[tid >> 4] = A;
    }

    // a-fragments in registers (RNE, r19-validated build; token = lc)
    short8v afr[8];
#pragma unroll
    for (int s = 0; s < 8; ++s) {
      unsigned short tmp[8];
#pragma unroll
      for (int j = 0; j < 8; ++j)
        tmp[j] = f32_to_bf16_rne(r_m[lc][s * 32 + lg * 8 + j]);
      afr[s] = (short8v){(short)tmp[0], (short)tmp[1], (short)tmp[2],
                         (short)tmp[3], (short)tmp[4], (short)tmp[5],
                         (short)tmp[6], (short)tmp[7]};
    }

    // ---- async-pipelined screen: 64 pairs (8 passes x 8 chunks) ----
    unsigned short* ring = &ringS[w][0];
    const unsigned short* cbase = cbf + ((size_t)lvl * 64 + w * 16) * 4096;

    f32x4 acc[2];
    acc[0] = (f32x4){0.f, 0.f, 0.f, 0.f};
    acc[1] = (f32x4){0.f, 0.f, 0.f, 0.f};

    // prologue: issue pairs 0..5 into slots 0..5
#pragma unroll
    for (int q = 0; q < 6; ++q) {
      const unsigned short* g0 = cbase + (q << 9) + lane * 8;  // p=0, s=q
      gload16(g0, ring + q * 1024);
      gload16(g0 + 4096, ring + q * 1024 + 512);
    }
    WVM(10);
    SBAR();
    short8v bA0 = *(const short8v*)(ring + lane * 8);
    short8v bA1 = *(const short8v*)(ring + 512 + lane * 8);
    int rs = 1;  // slot of next read (pair 1)
    int is = 0;  // slot of next issue (pair 6)

#pragma unroll 1
    for (int p = 0; p < 8; ++p) {
#pragma unroll
      for (int s = 0; s < 8; ++s) {
        acc[0] =
            __builtin_amdgcn_mfma_f32_16x16x32_bf16(afr[s], bA0, acc[0], 0, 0, 0);
        acc[1] =
            __builtin_amdgcn_mfma_f32_16x16x32_bf16(afr[s], bA1, acc[1], 0, 0, 0);
        SBAR();
        const int idx = p * 8 + s;
        if (idx < 63) {
          // wait for pair idx+1 (issued 6 pairs ahead; counted vmcnt)
          if (p < 7) {
            WVM(8);
          } else {
            if (s <= 2) {
              WVM(8);
            } else if (s == 3) {
              WVM(6);
            } else if (s == 4) {
              WVM(4);
            } else if (s == 5) {
              WVM(2);
            } else {
              WVM(0);
            }
          }
          SBAR();
          short8v nb0 = *(const short8v*)(ring + rs * 1024 + lane * 8);
          short8v nb1 = *(const short8v*)(ring + rs * 1024 + 512 + lane * 8);
          rs = (rs == 5) ? 0 : rs + 1;
          if (idx + 6 < 64) {
            WLK(2);  // pair idx's slot reads retired (only nb in flight)
            SBAR();
            const int n = idx + 6;
            const unsigned short* g0 =
                cbase + ((((n >> 3) * 16 + (n & 7)) << 9)) + lane * 8;
            gload16(g0, ring + is * 1024);
            gload16(g0 + 4096, ring + is * 1024 + 512);
            is = (is == 5) ? 0 : is + 1;
          }
          bA0 = nb0;
          bA1 = nb1;
        }
        if (s == 7) {
          // ---- transform + superset append for pass p ----
          float tmin[4];
          f32x4 sv[2];
#pragma unroll
          for (int reg = 0; reg < 4; ++reg) tmin[reg] = 3.4e38f;
#pragma unroll
          for (int f = 0; f < 2; ++f) {
            float Cv = C32g[lvl * KCB + (w * 16 + p * 2 + f) * 16 + lc];
            f32x4 sc;
#pragma unroll
            for (int reg = 0; reg < 4; ++reg) {
              float v = __fsub_rn(Cv, __fmul_rn(2.0f, acc[f][reg]));
              sc[reg] = v;
              tmin[reg] = fminf(tmin[reg], v);
            }
            sv[f] = sc;
          }
#pragma unroll
          for (int m = 1; m <= 8; m <<= 1)
#pragma unroll
            for (int reg = 0; reg < 4; ++reg)
              tmin[reg] = fminf(tmin[reg], __shfl_xor(tmin[reg], m));
          if (lc == 0) {
#pragma unroll
            for (int reg = 0; reg < 4; ++reg)
              atomicMin(&gkey[lg * 4 + reg], fkey(tmin[reg]));
          }
#pragma unroll
          for (int f = 0; f < 2; ++f)
#pragma unroll
            for (int reg = 0; reg < 4; ++reg) {
              int t = lg * 4 + reg;
              float th = finv(gkey[t]) + WWIN;
              if (sv[f][reg] <= th) {
                int slot = atomicAdd(&cnt[t], 1);
                if (slot < LCAP)
                  list[t][slot] = (w * 16 + p * 2 + f) * 16 + lc;
              }
            }
          acc[0] = (f32x4){0.f, 0.f, 0.f, 0.f};
          acc[1] = (f32x4){0.f, 0.f, 0.f, 0.f};
        }
      }
    }
    __syncthreads();  // lists, gkey, A_s final

    // ---- np-exact rescore (16 threads per token) ----
    {
      int t = tid >> 4;
      int kc = tid & 15;
      float A = A_s[t];
      float gminf = finv(gkey[t]);
      int n = cnt[t];
      float bd = 3.4e38f;
      int bk = KCB;
      if (n <= LCAP) {
        for (int ci = kc; ci < n; ci += 16) {
          int k = list[t][ci];
          float d = np_dist(&r_m[t][0], cb + (size_t)k * DIM, A,
                            C32g[lvl * KCB + k]);
          if (d < bd || (d == bd && k < bk)) {
            bd = d;
            bk = k;
          }
        }
      }
#pragma unroll
      for (int m = 1; m <= 8; m <<= 1) {
        float od = __shfl_xor(bd, m);
        int ok = __shfl_xor(bk, m);
        if (od < bd || (od == bd && ok < bk)) {
          bd = od;
          bk = ok;
        }
      }
      bool redo =
          (n > LCAP) || (fabsf(__fsub_rn(bd, A) - gminf) > (WWIN - ALARM));
      if (redo) {
        bd = 3.4e38f;
        bk = KCB;
        for (int k = kc; k < KCB; k += 16) {
          float d = np_dist(&r_m[t][0], cb + (size_t)k * DIM, A,
                            C32g[lvl * KCB + k]);
          if (d < bd || (d == bd && k < bk)) {
            bd = d;
            bk = k;
          }
        }
#pragma unroll
        for (int m = 1; m <= 8; m <<= 1) {
          float od = __shfl_xor(bd, m);
          int ok = __shfl_xor(bk, m);
          if (od < bd || (od == bd && ok < bk)) {
            bd = od;
            bk = ok;
          }
        }
      }
      if (kc == 0) {
        idx_s[t] = bk;
        out[(size_t)NTOK * DIM + (size_t)lvl * NTOK + n0 + t] = (float)bk;
      }
    }
    __syncthreads();

    // ---- residual update (exact) + next-level inits ----
    {
      int tok = tid >> 4;
      int db = (tid & 15) * 16;
      const float* crow = cb + (size_t)idx_s[tok] * DIM + db;
#pragma unroll
      for (int j = 0; j < 4; ++j) {
        float4 cv4 = *(const float4*)(crow + j * 4);
        int d = db + j * 4;
        r_m[tok][d + 0] = __fsub_rn(r_m[tok][d + 0], cv4.x);
        r_m[tok][d + 1] = __fsub_rn(r_m[tok][d + 1], cv4.y);
        r_m[tok][d + 2] = __fsub_rn(r_m[tok][d + 2], cv4.z);
        r_m[tok][d + 3] = __fsub_rn(r_m[tok][d + 3], cv4.w);
      }
      if (tid < TM) {
        gkey[tid] = 0xFFFFFFFFu;
        cnt[tid] = 0;
      }
    }
    __syncthreads();
  }

  // ---- straight_through = fl(l + fl(q - l)), q = fl(l - r) ----
  {
    int tok = tid >> 4;
    int db = (tid & 15) * 16;
#pragma unroll
    for (int j = 0; j < 4; ++j) {
      int d = db + j * 4;
      size_t gi = (size_t)(n0 + tok) * DIM + d;
      float4 l4 = *(const float4*)(latent + gi);
      float4 qv;
      float q;
      q = __fsub_rn(l4.x, r_m[tok][d + 0]);
      qv.x = __fadd_rn(l4.x, __fsub_rn(q, l4.x));
      q = __fsub_rn(l4.y, r_m[tok][d + 1]);
      qv.y = __fadd_rn(l4.y, __fsub_rn(q, l4.y));
      q = __fsub_rn(l4.z, r_m[tok][d + 2]);
      qv.z = __fadd_rn(l4.z, __fsub_rn(q, l4.z));
      q = __fsub_rn(l4.w, r_m[tok][d + 3]);
      qv.w = __fadd_rn(l4.w, __fsub_rn(q, l4.w));
      *(float4*)(out + gi) = qv;
    }
  }
}

extern "C" void kernel_launch(void* const* d_in, const int* in_sizes, int n_in,
                              void* d_out, int out_size, void* d_ws,
                              size_t ws_size, hipStream_t stream) {
  const float* latent = (const float*)d_in[0];
  const float* codebooks = (const float*)d_in[1];
  float* out = (float*)d_out;
  float* C32g = (float*)d_ws;                                    // 32 KB
  unsigned short* cbf = (unsigned short*)((char*)d_ws + 32768);  // 4 MB

  hipLaunchKernelGGL(c2_kernel, dim3(DEPTH * KCB / 256), dim3(256), 0, stream,
                     codebooks, C32g);
  hipLaunchKernelGGL(pack_kernel, dim3(DEPTH * 64 * 8 * 64 / 256), dim3(256),
                     0, stream, codebooks, cbf);
  hipLaunchKernelGGL(rvq_kernel, dim3(NTOK / TM), dim3(256), 0, stream, latent,
                     codebooks, C32g, cbf, out);
}